// Round 1
// baseline (585.456 us; speedup 1.0000x reference)
//
#include <hip/hip_runtime.h>

// FixedConv1DPriorEnsemble: DZ=30 ensemble of conv nets over embedded tokens.
// V=32000 E=8 DZ=30 C=10, CH=(4,8,8), K=3, S=(2,2,1), B=512, L=4096.
// L1=2047, L2=1023, L3=1021. Output [512,10] fp32.
//
// One block per (b, d): fused embed-gather -> conv1 -> conv2 -> conv3 ->
// mean-pool -> head, atomicAdd z[d]*pi into out[b][c].
// LDS: h1 [4][2048] (32KB) + h2 [8][1024] (32KB) + weights (~2KB) -> 2 blocks/CU.

#define L1_ 2047
#define L2_ 1023
#define L3_ 1021

__global__ void zero_out_kernel(float* __restrict__ out, int n) {
  int i = blockIdx.x * blockDim.x + threadIdx.x;
  if (i < n) out[i] = 0.0f;
}

__global__ __launch_bounds__(256) void ensemble_kernel(
    const int* __restrict__ ids,      // [512][4096]
    const float* __restrict__ mask,   // [512][4096]
    const float* __restrict__ z,      // [30]
    const float* __restrict__ tbl,    // [32000][8]
    const float* __restrict__ W1, const float* __restrict__ b1,   // [30][4][8][3], [30][4]
    const float* __restrict__ W2, const float* __restrict__ b2,   // [30][8][4][3], [30][8]
    const float* __restrict__ W3, const float* __restrict__ b3,   // [30][8][8][3], [30][8]
    const float* __restrict__ Wh, const float* __restrict__ bh,   // [30][10][8], [30][10]
    float* __restrict__ out)          // [512][10]
{
  const int tid = threadIdx.x;
  const int b = blockIdx.x & 511;   // grid = 512*30
  const int d = blockIdx.x >> 9;

  __shared__ float sW1[96], sB1[4];
  __shared__ float sW2[96], sB2[8];
  __shared__ float sW3[192], sB3[8];
  __shared__ float sWh[80], sBh[10];
  __shared__ float h1[4 * 2048];   // 32 KB
  __shared__ float h2[8 * 1024];   // 32 KB
  __shared__ float red[4 * 8];
  __shared__ float pooled[8];

  // ---- stage weights into LDS (block-uniform) ----
  for (int i = tid; i < 96;  i += 256) sW1[i] = W1[d * 96  + i];
  for (int i = tid; i < 96;  i += 256) sW2[i] = W2[d * 96  + i];
  for (int i = tid; i < 192; i += 256) sW3[i] = W3[d * 192 + i];
  for (int i = tid; i < 80;  i += 256) sWh[i] = Wh[d * 80  + i];
  if (tid < 4)                      sB1[tid]       = b1[d * 4  + tid];
  else if (tid >= 64  && tid < 72)  sB2[tid - 64]  = b2[d * 8  + tid - 64];
  else if (tid >= 128 && tid < 136) sB3[tid - 128] = b3[d * 8  + tid - 128];
  else if (tid >= 192 && tid < 202) sBh[tid - 192] = bh[d * 10 + tid - 192];
  __syncthreads();

  const int*   idrow = ids  + (size_t)b * 4096;
  const float* mrow  = mask + (size_t)b * 4096;
  const float4* tbl4 = (const float4*)tbl;   // table rows are 8 floats = 2x float4

  // ---- stage 1: conv1 (E=8 -> 4 ch, K=3, stride 2), gather embeds on the fly ----
  {
    float w1r[96];
    #pragma unroll
    for (int i = 0; i < 96; ++i) w1r[i] = sW1[i];

    for (int l = tid; l < L1_; l += 256) {
      const int p = 2 * l;
      float xv[24];
      #pragma unroll
      for (int k = 0; k < 3; ++k) {
        const int id = idrow[p + k];
        const float m = mrow[p + k];
        float4 a = tbl4[(size_t)id * 2];
        float4 c = tbl4[(size_t)id * 2 + 1];
        xv[k * 8 + 0] = a.x * m; xv[k * 8 + 1] = a.y * m;
        xv[k * 8 + 2] = a.z * m; xv[k * 8 + 3] = a.w * m;
        xv[k * 8 + 4] = c.x * m; xv[k * 8 + 5] = c.y * m;
        xv[k * 8 + 6] = c.z * m; xv[k * 8 + 7] = c.w * m;
      }
      #pragma unroll
      for (int c = 0; c < 4; ++c) {
        float acc = sB1[c];
        #pragma unroll
        for (int e = 0; e < 8; ++e)
          #pragma unroll
          for (int k = 0; k < 3; ++k)
            acc += xv[k * 8 + e] * w1r[c * 24 + e * 3 + k];
        h1[c * 2048 + l] = fmaxf(acc, 0.0f);
      }
    }
  }
  __syncthreads();

  // ---- stage 2: conv2 (4 -> 8 ch, K=3, stride 2) ----
  {
    float w2r[96];
    #pragma unroll
    for (int i = 0; i < 96; ++i) w2r[i] = sW2[i];

    for (int j = tid; j < L2_; j += 256) {
      float hv[12];
      #pragma unroll
      for (int c1 = 0; c1 < 4; ++c1)
        #pragma unroll
        for (int k = 0; k < 3; ++k)
          hv[c1 * 3 + k] = h1[c1 * 2048 + 2 * j + k];
      #pragma unroll
      for (int c2 = 0; c2 < 8; ++c2) {
        float acc = sB2[c2];
        #pragma unroll
        for (int jj = 0; jj < 12; ++jj)
          acc += hv[jj] * w2r[c2 * 12 + jj];
        h2[c2 * 1024 + j] = fmaxf(acc, 0.0f);
      }
    }
  }
  __syncthreads();

  // ---- stage 3: conv3 (8 -> 8 ch, K=3, stride 1) + relu + pool-sum in regs ----
  float psum[8];
  #pragma unroll
  for (int c = 0; c < 8; ++c) psum[c] = 0.0f;

  #pragma unroll 1
  for (int half = 0; half < 2; ++half) {   // split c3 to keep VGPRs in budget
    float w3r[96];
    #pragma unroll
    for (int i = 0; i < 96; ++i) w3r[i] = sW3[half * 96 + i];

    for (int i = tid; i < L3_; i += 256) {
      float hv[24];
      #pragma unroll
      for (int c2 = 0; c2 < 8; ++c2)
        #pragma unroll
        for (int k = 0; k < 3; ++k)
          hv[c2 * 3 + k] = h2[c2 * 1024 + i + k];
      #pragma unroll
      for (int cc = 0; cc < 4; ++cc) {
        float acc = sB3[half * 4 + cc];
        #pragma unroll
        for (int jj = 0; jj < 24; ++jj)
          acc += hv[jj] * w3r[cc * 24 + jj];
        psum[half * 4 + cc] += fmaxf(acc, 0.0f);
      }
    }
  }

  // ---- reduce pooled sums across the block ----
  const int lane = tid & 63;
  const int wid  = tid >> 6;
  #pragma unroll
  for (int c = 0; c < 8; ++c) {
    float v = psum[c];
    #pragma unroll
    for (int off = 32; off > 0; off >>= 1) v += __shfl_down(v, off, 64);
    if (lane == 0) red[wid * 8 + c] = v;
  }
  __syncthreads();
  if (tid < 8)
    pooled[tid] = red[tid] + red[8 + tid] + red[16 + tid] + red[24 + tid];
  __syncthreads();

  // ---- head: pi[c] = mean(pooled) @ Wh^T + bh; out[b][c] += z[d] * pi[c] ----
  if (tid < 10) {
    float acc = sBh[tid];
    #pragma unroll
    for (int c3 = 0; c3 < 8; ++c3)
      acc += pooled[c3] * (1.0f / 1021.0f) * sWh[tid * 8 + c3];
    atomicAdd(&out[b * 10 + tid], z[d] * acc);
  }
}

extern "C" void kernel_launch(void* const* d_in, const int* in_sizes, int n_in,
                              void* d_out, int out_size, void* d_ws, size_t ws_size,
                              hipStream_t stream) {
  const int*   ids  = (const int*)d_in[0];
  const float* mask = (const float*)d_in[1];
  const float* z    = (const float*)d_in[2];
  const float* tbl  = (const float*)d_in[3];
  const float* W1   = (const float*)d_in[4];
  const float* b1   = (const float*)d_in[5];
  const float* W2   = (const float*)d_in[6];
  const float* b2   = (const float*)d_in[7];
  const float* W3   = (const float*)d_in[8];
  const float* b3   = (const float*)d_in[9];
  const float* Wh   = (const float*)d_in[10];
  const float* bh   = (const float*)d_in[11];
  float* out = (float*)d_out;

  hipLaunchKernelGGL(zero_out_kernel, dim3(20), dim3(256), 0, stream, out, 5120);
  hipLaunchKernelGGL(ensemble_kernel, dim3(512 * 30), dim3(256), 0, stream,
                     ids, mask, z, tbl, W1, b1, W2, b2, W3, b3, Wh, bh, out);
}